// Round 8
// baseline (42.045 us; speedup 1.0000x reference)
//
#include <hip/hip_runtime.h>

// ---------------------------------------------------------------------------
// PodNetClassifier: out[b][c] = sum_k simi*softmax_k(simi),
//   simi[b,c,k] = -max(2 - 2*dot(a_b, th_{c*10+k}), 0)  (unit vectors)
// Round 8: full-line output stores. BN=160 (16 classes/block) so each block
// writes whole 64B lines (no cross-block/cross-XCD partial lines -> no HBM
// RMW). BM=128, 63 n-blocks (tail clamped/masked). Epilogue: lane owns
// 4 rows x 1 class, f32x4 reads, packed 4-row softmax.
// ---------------------------------------------------------------------------

#define BATCH   8192
#define DIM     64
#define KPROX   10
#define NCLASS  1000
#define NCOL    (NCLASS * KPROX)   // 10000
#define NBTILE  (BATCH / 16)       // 512
#define NNTILE  (NCOL / 16)        // 625 (tiles 0..624)

#define BM      128                // rows per block (4 waves x 32)
#define BN      160                // proxies per block = 16 classes = 10 tiles
#define TPB     10                 // mfma col tiles per block
#define NBM     (BATCH / BM)       // 64
#define NBN     63                 // ceil(10000/160): last block half-masked
#define CSTR    20                 // LDS words per proxy-column (16 rows + pad)

#define XBLKS   (NBTILE / 4)         // 128 prep blocks for x
#define TBLKS   ((NCOL + 255) / 256) // 40 prep blocks for theta

typedef __attribute__((ext_vector_type(8))) short bf16x8;
typedef __attribute__((ext_vector_type(4))) float f32x4;

#define LOG2E 1.4426950408889634f
#define LN2   0.6931471805599453f

__device__ inline unsigned short f32_to_bf16(float f) {
    unsigned int u = __float_as_uint(f);
    u += 0x7FFFu + ((u >> 16) & 1u);   // round-to-nearest-even
    return (unsigned short)(u >> 16);
}

// ---- merged prep: blocks [0,128) pack x, blocks [128,168) pack theta -------
// X planes: Xf_p[(bt*64 + lane)*8 + i] = a[bt*16 + (lane&15)][p*32 + (lane>>4)*8 + i]
// TH planes: same fragment layout over proxy rows j = c*10+kk.
__global__ __launch_bounds__(256)
void prep_kernel(const float* __restrict__ x, const float* __restrict__ theta,
                 unsigned short* __restrict__ Xf0, unsigned short* __restrict__ Xf1,
                 unsigned short* __restrict__ THf0, unsigned short* __restrict__ THf1) {
    if (blockIdx.x < XBLKS) {
        int wave = threadIdx.x >> 6, lane = threadIdx.x & 63;
        int bt  = blockIdx.x * 4 + wave;
        int r16 = lane & 15, hi = lane >> 4;
        const float* src = x + (size_t)(bt * 16 + r16) * DIM + hi * 8;
        f32x4 v0 = *(const f32x4*)(src);
        f32x4 v1 = *(const f32x4*)(src + 4);
        f32x4 v2 = *(const f32x4*)(src + 32);
        f32x4 v3 = *(const f32x4*)(src + 36);
        float ss = 0.f;
        #pragma unroll
        for (int i = 0; i < 4; ++i)
            ss += v0[i]*v0[i] + v1[i]*v1[i] + v2[i]*v2[i] + v3[i]*v3[i];
        ss += __shfl_xor(ss, 16);
        ss += __shfl_xor(ss, 32);
        float sc = __builtin_amdgcn_rsqf(ss);   // norms are O(8), no eps needed
        bf16x8 p0, p1;
        #pragma unroll
        for (int i = 0; i < 4; ++i) {
            p0[i]     = (short)f32_to_bf16(v0[i] * sc);
            p0[i + 4] = (short)f32_to_bf16(v1[i] * sc);
            p1[i]     = (short)f32_to_bf16(v2[i] * sc);
            p1[i + 4] = (short)f32_to_bf16(v3[i] * sc);
        }
        ((bf16x8*)Xf0)[bt * 64 + lane] = p0;
        ((bf16x8*)Xf1)[bt * 64 + lane] = p1;
    } else {
        int tid = (blockIdx.x - XBLKS) * 256 + threadIdx.x;
        if (tid >= NCOL) return;
        int kk = tid / NCLASS, c = tid - kk * NCLASS;  // consecutive tid -> consecutive c
        const float* src = theta + kk * NCLASS + c;
        float v[DIM];
        float ss = 0.f;
        #pragma unroll
        for (int d = 0; d < DIM; ++d) {
            v[d] = src[(size_t)d * NCOL];
            ss += v[d] * v[d];
        }
        float sc = __builtin_amdgcn_rsqf(ss);
        int j = c * KPROX + kk;
        int jt = j >> 4, jr = j & 15;
        #pragma unroll
        for (int h = 0; h < 8; ++h) {      // chunk h holds d = h*8 .. h*8+7
            unsigned short* dst = (h < 4 ? THf0 : THf1)
                                + ((size_t)jt * 64 + (h & 3) * 16 + jr) * 8;
            #pragma unroll
            for (int i = 0; i < 8; ++i)
                dst[i] = f32_to_bf16(v[h * 8 + i] * sc);
        }
    }
}

// ---- main: 32x160 wave tiles, full-line coalesced stores -------------------
__global__ __launch_bounds__(256, 3)
void podnet_main(const unsigned short* __restrict__ Xf0,
                 const unsigned short* __restrict__ Xf1,
                 const unsigned short* __restrict__ THf0,
                 const unsigned short* __restrict__ THf1,
                 float* __restrict__ out) {
    __shared__ float S[4][BN][CSTR];   // 51.2 KB, wave-private slabs

    int bm = blockIdx.x / NBN, bn = blockIdx.x % NBN;
    int wave = threadIdx.x >> 6, lane = threadIdx.x & 63;

    const bf16x8* xf0 = (const bf16x8*)Xf0;
    const bf16x8* xf1 = (const bf16x8*)Xf1;
    const bf16x8* tf0 = (const bf16x8*)THf0;
    const bf16x8* tf1 = (const bf16x8*)THf1;

    int ab = (bm * 8 + wave * 2) * 64 + lane;   // 2 row-tiles per wave

    // ---- all 24 loads issued back-to-back, pinned before any compute ------
    bf16x8 a0[2], a1[2], b0[TPB], b1[TPB];
    #pragma unroll
    for (int k = 0; k < 2; ++k) { a0[k] = xf0[ab + k * 64]; a1[k] = xf1[ab + k * 64]; }
    #pragma unroll
    for (int t = 0; t < TPB; ++t) {
        int ti = bn * TPB + t;               // clamp tail (bn=62: tiles 625..629)
        ti = ti > (NNTILE - 1) ? (NNTILE - 1) : ti;
        b0[t] = tf0[ti * 64 + lane];
        b1[t] = tf1[ti * 64 + lane];
    }
    __builtin_amdgcn_sched_barrier(0);

    int r16 = lane & 15, hi = lane >> 4;     // writer: proxy-col r16 (per tile)
    int g   = lane & 15, rq = lane >> 4;     // reader: class g, row-quad rq
    bool stok = (bn * 16 + g) < NCLASS;      // tail class mask

    #pragma unroll
    for (int k = 0; k < 2; ++k) {
        // 20 MFMAs for this 16-row x 160-proxy slab
        f32x4 acc[TPB];
        #pragma unroll
        for (int t = 0; t < TPB; ++t) {
            f32x4 c = {0.f, 0.f, 0.f, 0.f};
            c = __builtin_amdgcn_mfma_f32_16x16x32_bf16(a0[k], b0[t], c, 0, 0, 0);
            c = __builtin_amdgcn_mfma_f32_16x16x32_bf16(a1[k], b1[t], c, 0, 0, 0);
            acc[t] = c;
        }
        // scores -> LDS, pre-scaled by log2e: y = (2s-2)*log2e, y <= 0
        // acc[t][r]: x-row hi*4+r, proxy t*16+r16
        #pragma unroll
        for (int t = 0; t < TPB; ++t) {
            f32x4 s;
            #pragma unroll
            for (int r = 0; r < 4; ++r)
                s[r] = fminf(fmaf(acc[t][r], 2.0f * LOG2E, -2.0f * LOG2E), 0.f);
            *(f32x4*)&S[wave][t * 16 + r16][hi * 4] = s;
        }
        // softmax over 10: lane owns class g, rows rq*4..rq*4+3 (packed f32x4)
        f32x4 ps = {0.f, 0.f, 0.f, 0.f}, ws = {0.f, 0.f, 0.f, 0.f};
        #pragma unroll
        for (int i = 0; i < KPROX; ++i) {
            f32x4 v = *(const f32x4*)&S[wave][g * 10 + i][rq * 4];
            f32x4 e;
            #pragma unroll
            for (int j = 0; j < 4; ++j) e[j] = exp2f(v[j]);  // y in [-5.77,0]
            ps += e;
            ws += v * e;
        }
        // stores: 16 g-lanes x 4 rows -> 4 full 64B lines per store instr
        size_t xr0 = (size_t)bm * BM + wave * 32 + k * 16 + rq * 4;
        float* op = out + xr0 * NCLASS + bn * 16 + g;
        #pragma unroll
        for (int rr = 0; rr < 4; ++rr) {
            float o = ws[rr] * __builtin_amdgcn_rcpf(ps[rr]) * LN2;
            if (stok) __builtin_nontemporal_store(o, op + (size_t)rr * NCLASS);
        }
    }
}

extern "C" void kernel_launch(void* const* d_in, const int* in_sizes, int n_in,
                              void* d_out, int out_size, void* d_ws, size_t ws_size,
                              hipStream_t stream) {
    const float* x     = (const float*)d_in[0];   // (8192, 64)
    const float* theta = (const float*)d_in[1];   // (64, 10, 1000)
    float* out = (float*)d_out;                   // (8192, 1000) f32

    unsigned short* Xf0 = (unsigned short*)d_ws;       // 512 KB each X plane
    unsigned short* Xf1 = Xf0 + (size_t)NBTILE * 512;
    unsigned short* Tf0 = Xf1 + (size_t)NBTILE * 512;  // 640 KB each TH plane
    unsigned short* Tf1 = Tf0 + (size_t)NNTILE * 512;

    prep_kernel<<<XBLKS + TBLKS, 256, 0, stream>>>(x, theta, Xf0, Xf1, Tf0, Tf1);
    podnet_main<<<NBM * NBN, 256, 0, stream>>>(Xf0, Xf1, Tf0, Tf1, out);
}